// Round 1
// baseline (591.320 us; speedup 1.0000x reference)
//
#include <hip/hip_runtime.h>
#include <math.h>

#define NODES_TOTAL 160000
#define NODES_REAL  5000
#define D 128
#define NEG 0.2f
#define KP 136                // padded k-pitch (ushorts) for gsmall's LDS ds_read_b128
#define HL (128 * KP)         // ushorts per hi (or lo) block = 17408
#define WT_L (2 * HL)         // ushorts per layer (hi + lo)  = 34816
#define KP2 128               // unpadded pitch for mlp3's direct-from-L2 B reads
#define HL2 (128 * KP2)       // 16384
#define WT2_L (2 * HL2)       // 32768

typedef unsigned short ushort_t;
typedef unsigned int uint_t;
typedef __attribute__((ext_vector_type(8))) __bf16 bf16x8;
typedef __attribute__((ext_vector_type(4))) float f32x4;
union BF8 { bf16x8 v; ushort_t u[8]; };

__device__ __forceinline__ void split2(float x, ushort_t& hi, ushort_t& lo) {
    unsigned u = __float_as_uint(x);
    hi = (ushort_t)(u >> 16);
    float hif = __uint_as_float(u & 0xffff0000u);
    lo = (ushort_t)(__float_as_uint(x - hif) >> 16);
}
__device__ __forceinline__ uint_t encmax(float f) {
    uint_t b = __float_as_uint(f);
    return b ^ ((uint_t)((int)b >> 31) | 0x80000000u);
}
__device__ __forceinline__ float decmax(uint_t u) {
    uint_t b = (u & 0x80000000u) ? (u ^ 0x80000000u) : ~u;
    return __uint_as_float(b);
}

// ---------------- CSR build ----------------------------------------------------
__global__ void zero_kernel(int* counts, uint_t* gmaxu) {
    int i = blockIdx.x * blockDim.x + threadIdx.x;
    if (i < NODES_REAL) counts[i] = 0;
    if (i < 3) gmaxu[i] = 0u;
}

__global__ void rank_kernel(const int* __restrict__ ei, int* __restrict__ counts,
                            ushort_t* __restrict__ rank16, int Eh) {
    int e = blockIdx.x * blockDim.x + threadIdx.x;
    if (e < Eh) {
        int d = ei[Eh + e];
        int r = atomicAdd(&counts[d], 1);
        rank16[e] = (ushort_t)r;
    }
}

__global__ void scan_kernel(const int* __restrict__ counts, int* __restrict__ offs) {
    __shared__ int sd[1024];
    int t = threadIdx.x;
    int pre[5]; int sum = 0;
    #pragma unroll
    for (int u = 0; u < 5; ++u) {
        int idx = t * 5 + u;
        int c = (idx < NODES_REAL) ? counts[idx] : 0;
        pre[u] = sum; sum += c;
    }
    sd[t] = sum;
    __syncthreads();
    int run = sum;
    for (int o = 1; o < 1024; o <<= 1) {
        int v = (t >= o) ? sd[t - o] : 0;
        __syncthreads();
        sd[t] += v;
        __syncthreads();
    }
    int excl = sd[t] - run;
    #pragma unroll
    for (int u = 0; u < 5; ++u) {
        int idx = t * 5 + u;
        if (idx < NODES_REAL) offs[idx] = excl + pre[u];
    }
    if (t == 1023) offs[NODES_REAL] = excl + run;
}

// deterministic scatter, u16 payload (src < 5000)
__global__ void scatter_det(const int* __restrict__ ei, const int* __restrict__ offs,
                            const ushort_t* __restrict__ rank16, ushort_t* __restrict__ esrc,
                            int Eh) {
    int e = blockIdx.x * blockDim.x + threadIdx.x;
    if (e < Eh) {
        int s = ei[e];
        int d = ei[Eh + e];
        esrc[offs[d] + (int)rank16[e]] = (ushort_t)s;
    }
}

// ---------------- W split+transpose: padded copy (gsmall/LDS) + unpadded (mlp3) -
__global__ void wsplit_kernel(const float* __restrict__ Ws, ushort_t* __restrict__ Wt,
                              ushort_t* __restrict__ Wu) {
    int l  = blockIdx.x >> 3;
    int n  = (blockIdx.x & 7) * 16 + (threadIdx.x >> 4);
    int k0 = (threadIdx.x & 15) * 8;
    const float* src = Ws + (size_t)l * D * D;
    union { ushort_t u[8]; uint4 v; } hi, lo;
    #pragma unroll
    for (int j = 0; j < 8; ++j) split2(src[(size_t)(k0 + j) * D + n], hi.u[j], lo.u[j]);
    ushort_t* dhi = Wt + (size_t)l * WT_L + n * KP + k0;
    *(uint4*)dhi = hi.v;
    *(uint4*)(dhi + HL) = lo.v;
    ushort_t* dhi2 = Wu + (size_t)l * WT2_L + n * KP2 + k0;
    *(uint4*)dhi2 = hi.v;
    *(uint4*)(dhi2 + HL2) = lo.v;
}

// ---------------- fused 3-layer MLP for rows [5000,160000) ---------------------
// B-fragments read directly from the L2-resident unpadded weight buffer (196KB,
// each wave-load = 16 aligned 64B segments). LDS = per-wave scratch only
// (67.6KB) -> 2 blocks/CU (2 waves/SIMD), and only 2 barriers total.
__global__ __launch_bounds__(256, 2)
void mlp3_kernel(const float* __restrict__ x, const ushort_t* __restrict__ Wu,
                 const float* __restrict__ bs, float* __restrict__ out) {
    __shared__ float scr[4][2][16][132];   // 67584 B
    int tid = threadIdx.x;
    int w = tid >> 6, lane = tid & 63, q = lane >> 4, m16 = lane & 15;
    int row0 = NODES_REAL + blockIdx.x * 128 + w * 32;

    // prefetch layer-0 A tiles into registers
    float4 xa[2][4][2];
    #pragma unroll
    for (int rt = 0; rt < 2; ++rt) {
        int r = row0 + rt * 16 + m16;
        if (r > NODES_TOTAL - 1) r = NODES_TOTAL - 1;
        #pragma unroll
        for (int kc = 0; kc < 4; ++kc) {
            const float* gp = x + (size_t)r * D + kc * 32 + q * 8;
            xa[rt][kc][0] = *(const float4*)gp;
            xa[rt][kc][1] = *(const float4*)(gp + 4);
        }
    }

    f32x4 acc[2][8];
    #pragma unroll
    for (int l = 0; l < 3; ++l) {
        if (l > 0) __syncthreads();   // scr write(layer l-1) -> cross-lane read fence
        const ushort_t* Wb = Wu + (size_t)l * WT2_L + m16 * KP2 + q * 8;

        #pragma unroll
        for (int rt = 0; rt < 2; ++rt)
            #pragma unroll
            for (int ct = 0; ct < 8; ++ct) acc[rt][ct] = (f32x4){0.f, 0.f, 0.f, 0.f};

        #pragma unroll
        for (int kc = 0; kc < 4; ++kc) {
            BF8 ahi[2], alo[2];
            #pragma unroll
            for (int rt = 0; rt < 2; ++rt) {
                float xv[8];
                if (l == 0) {
                    float4 v0 = xa[rt][kc][0], v1 = xa[rt][kc][1];
                    xv[0]=v0.x; xv[1]=v0.y; xv[2]=v0.z; xv[3]=v0.w;
                    xv[4]=v1.x; xv[5]=v1.y; xv[6]=v1.z; xv[7]=v1.w;
                } else {
                    const float* sp = &scr[w][rt][m16][kc * 32 + q * 8];
                    float4 v0 = *(const float4*)sp, v1 = *(const float4*)(sp + 4);
                    xv[0]=v0.x; xv[1]=v0.y; xv[2]=v0.z; xv[3]=v0.w;
                    xv[4]=v1.x; xv[5]=v1.y; xv[6]=v1.z; xv[7]=v1.w;
                }
                #pragma unroll
                for (int j = 0; j < 8; ++j) split2(xv[j], ahi[rt].u[j], alo[rt].u[j]);
            }
            #pragma unroll
            for (int ct = 0; ct < 8; ++ct) {
                const ushort_t* bp = Wb + ct * 16 * KP2 + kc * 32;
                bf16x8 bhi = *(const bf16x8*)bp;
                bf16x8 blo = *(const bf16x8*)(bp + HL2);
                #pragma unroll
                for (int rt = 0; rt < 2; ++rt) {
                    acc[rt][ct] = __builtin_amdgcn_mfma_f32_16x16x32_bf16(ahi[rt].v, bhi, acc[rt][ct], 0, 0, 0);
                    acc[rt][ct] = __builtin_amdgcn_mfma_f32_16x16x32_bf16(ahi[rt].v, blo, acc[rt][ct], 0, 0, 0);
                    acc[rt][ct] = __builtin_amdgcn_mfma_f32_16x16x32_bf16(alo[rt].v, bhi, acc[rt][ct], 0, 0, 0);
                }
            }
        }
        // relu(h2 + b) -> per-wave scratch (C-layout in; A-layout read next layer,
        // linear read for the final store). Wave-private: no block hazard.
        float bv[8];
        #pragma unroll
        for (int ct = 0; ct < 8; ++ct) bv[ct] = bs[l * D + ct * 16 + m16];
        #pragma unroll
        for (int rt = 0; rt < 2; ++rt)
            #pragma unroll
            for (int ct = 0; ct < 8; ++ct)
                #pragma unroll
                for (int reg = 0; reg < 4; ++reg)
                    scr[w][rt][q * 4 + reg][ct * 16 + m16] =
                        fmaxf(acc[rt][ct][reg] + bv[ct], 0.f);
    }
    // coalesced epilogue: wave streams its 32 rows x 128 cols from scr,
    // consecutive lanes -> consecutive 16B -> 1KB per store instruction.
    // (within-wave cross-lane LDS write->read without barrier: proven pattern.)
    #pragma unroll
    for (int i = 0; i < 16; ++i) {
        int rowl = i * 2 + (lane >> 5);          // 0..31
        int rt = rowl >> 4, r16 = rowl & 15;
        int grow = row0 + rowl;
        float4 v = *(const float4*)&scr[w][rt][r16][(lane & 31) * 4];
        if (grow < NODES_TOTAL)
            *(float4*)&out[(size_t)grow * D + (lane & 31) * 4] = v;
    }
}

// ---------------- small GEMM (rows<5000) + fused scores + per-layer max --------
__global__ __launch_bounds__(256)
void gsmall_kernel(const float* __restrict__ hin, const ushort_t* __restrict__ Wlg,
                   const float* __restrict__ a_s, const float* __restrict__ a_d,
                   float* __restrict__ h2, float* __restrict__ sv, float* __restrict__ dv,
                   uint_t* __restrict__ gmaxu) {
    __shared__ ushort_t Wl[WT_L];
    int tid = threadIdx.x;
    {
        const uint4* gw = (const uint4*)Wlg;
        uint4* lw = (uint4*)Wl;
        #pragma unroll
        for (int r = 0; r < 17; ++r) lw[r * 256 + tid] = gw[r * 256 + tid];
    }
    int w = tid >> 6, lane = tid & 63, q = lane >> 4, m16 = lane & 15;
    int row0 = blockIdx.x * 128 + w * 32;
    f32x4 acc[2][8];
    #pragma unroll
    for (int rt = 0; rt < 2; ++rt)
        #pragma unroll
        for (int ct = 0; ct < 8; ++ct) acc[rt][ct] = (f32x4){0.f, 0.f, 0.f, 0.f};
    // prefetch A while W stages
    float4 xa[2][4][2];
    #pragma unroll
    for (int rt = 0; rt < 2; ++rt) {
        int r = row0 + rt * 16 + m16;
        if (r > NODES_REAL - 1) r = NODES_REAL - 1;
        #pragma unroll
        for (int kc = 0; kc < 4; ++kc) {
            const float* gp = hin + (size_t)r * D + kc * 32 + q * 8;
            xa[rt][kc][0] = *(const float4*)gp;
            xa[rt][kc][1] = *(const float4*)(gp + 4);
        }
    }
    __syncthreads();
    #pragma unroll
    for (int kc = 0; kc < 4; ++kc) {
        BF8 ahi[2], alo[2];
        #pragma unroll
        for (int rt = 0; rt < 2; ++rt) {
            float4 v0 = xa[rt][kc][0], v1 = xa[rt][kc][1];
            float xv[8] = {v0.x, v0.y, v0.z, v0.w, v1.x, v1.y, v1.z, v1.w};
            #pragma unroll
            for (int j = 0; j < 8; ++j) split2(xv[j], ahi[rt].u[j], alo[rt].u[j]);
        }
        #pragma unroll
        for (int ct = 0; ct < 8; ++ct) {
            const ushort_t* bp = Wl + (ct * 16 + m16) * KP + kc * 32 + q * 8;
            bf16x8 bhi = *(const bf16x8*)bp;
            bf16x8 blo = *(const bf16x8*)(bp + HL);
            #pragma unroll
            for (int rt = 0; rt < 2; ++rt) {
                acc[rt][ct] = __builtin_amdgcn_mfma_f32_16x16x32_bf16(ahi[rt].v, bhi, acc[rt][ct], 0, 0, 0);
                acc[rt][ct] = __builtin_amdgcn_mfma_f32_16x16x32_bf16(ahi[rt].v, blo, acc[rt][ct], 0, 0, 0);
                acc[rt][ct] = __builtin_amdgcn_mfma_f32_16x16x32_bf16(alo[rt].v, bhi, acc[rt][ct], 0, 0, 0);
            }
        }
    }
    #pragma unroll
    for (int rt = 0; rt < 2; ++rt)
        #pragma unroll
        for (int reg = 0; reg < 4; ++reg) {
            int grow = row0 + rt * 16 + q * 4 + reg;
            if (grow < NODES_REAL) {
                #pragma unroll
                for (int ct = 0; ct < 8; ++ct)
                    h2[(size_t)grow * D + ct * 16 + m16] = acc[rt][ct][reg];
            }
        }
    float asv[8], adv[8];
    #pragma unroll
    for (int ct = 0; ct < 8; ++ct) { asv[ct] = a_s[ct * 16 + m16]; adv[ct] = a_d[ct * 16 + m16]; }
    #pragma unroll
    for (int rt = 0; rt < 2; ++rt)
        #pragma unroll
        for (int reg = 0; reg < 4; ++reg) {
            float ps = 0.f, pd = 0.f;
            #pragma unroll
            for (int ct = 0; ct < 8; ++ct) {
                float v = acc[rt][ct][reg];
                ps += v * asv[ct]; pd += v * adv[ct];
            }
            #pragma unroll
            for (int o = 1; o < 16; o <<= 1) { ps += __shfl_xor(ps, o); pd += __shfl_xor(pd, o); }
            int grow = row0 + rt * 16 + q * 4 + reg;
            if (m16 == 0 && grow < NODES_REAL) {
                sv[grow] = ps; dv[grow] = pd;
                atomicMax(gmaxu, encmax(ps));
            }
        }
}

// ---------------- aggregation: one wave per dst, global-bound softmax ----------
__global__ __launch_bounds__(256)
void agg_kernel(const float* __restrict__ h2, const float* __restrict__ sv,
                const float* __restrict__ dv, const int* __restrict__ offs,
                const ushort_t* __restrict__ esrc, const float* __restrict__ bias,
                float* __restrict__ out, const uint_t* __restrict__ gmaxu) {
    int w = threadIdx.x >> 6, lane = threadIdx.x & 63;
    int i = blockIdx.x * 4 + w;
    int start = offs[i], end = offs[i + 1];
    float d_i = dv[i];
    float gm = decmax(*gmaxu) + d_i;       // upper bound on every incoming score
    float m = gm > 0.f ? gm : NEG * gm;    // leaky_relu monotone -> exact shift
    float ax = 0.f, ay = 0.f, ax1 = 0.f, ay1 = 0.f, exs = 0.f;
    for (int base = start; base < end; base += 64) {
        int cnt = min(64, end - base);
        int srci = (lane < cnt) ? (int)esrc[base + lane] : 0;
        float sc = sv[srci] + d_i;
        sc = sc > 0.f ? sc : NEG * sc;
        float ex = (lane < cnt) ? __expf(sc - m) : 0.f;
        exs += ex;
        if (cnt == 64) {
            #pragma unroll 4
            for (int j = 0; j < 64; j += 2) {   // 2 independent fmac chains
                int   s0 = __shfl(srci, j),     s1 = __shfl(srci, j + 1);
                float e0 = __shfl(ex, j),       e1 = __shfl(ex, j + 1);
                float2 h0 = *(const float2*)&h2[(size_t)s0 * D + 2 * lane];
                float2 h1 = *(const float2*)&h2[(size_t)s1 * D + 2 * lane];
                ax  += e0 * h0.x; ay  += e0 * h0.y;
                ax1 += e1 * h1.x; ay1 += e1 * h1.y;
            }
        } else {
            for (int j = 0; j < cnt; ++j) {
                int   src = __shfl(srci, j);
                float e   = __shfl(ex, j);
                float2 hv = *(const float2*)&h2[(size_t)src * D + 2 * lane];
                ax += e * hv.x; ay += e * hv.y;
            }
        }
    }
    ax += ax1; ay += ay1;
    float scf = sv[i] + d_i; scf = scf > 0.f ? scf : NEG * scf;
    float exf = __expf(scf - m);
    float2 hv = *(const float2*)&h2[(size_t)i * D + 2 * lane];
    ax += exf * hv.x; ay += exf * hv.y;
    #pragma unroll
    for (int o = 1; o < 64; o <<= 1) exs += __shfl_xor(exs, o);
    float rd = 1.f / (exs + exf);
    float2 b2 = *(const float2*)&bias[2 * lane];
    float2 o2 = make_float2(fmaxf(ax * rd + b2.x, 0.f), fmaxf(ay * rd + b2.y, 0.f));
    *(float2*)&out[(size_t)i * D + 2 * lane] = o2;
}

// ---------------- launcher -----------------------------------------------------
extern "C" void kernel_launch(void* const* d_in, const int* in_sizes, int n_in,
                              void* d_out, int out_size, void* d_ws, size_t ws_size,
                              hipStream_t stream) {
    const float* x   = (const float*)d_in[0];
    const int*   ei  = (const int*)d_in[1];
    const float* Ws  = (const float*)d_in[2];
    const float* as_ = (const float*)d_in[3];
    const float* ad_ = (const float*)d_in[4];
    const float* bs  = (const float*)d_in[5];
    float* out = (float*)d_out;
    int Eh = in_sizes[1] / 2;                    // 1,280,000

    char* ws = (char*)d_ws;
    float*    h2     = (float*)ws;                        //  2,560,000
    float*    bufS   = (float*)(ws + 2560000);            //  2,560,000
    float*    sv     = (float*)(ws + 5120000);            //     20,000
    float*    dv     = (float*)(ws + 5140000);            //     20,000
    int*      counts = (int*)  (ws + 5160000);            //     20,000
    int*      offs   = (int*)  (ws + 5180000);            //     20,016
    ushort_t* rank16 = (ushort_t*)(ws + 5200016);         //  2,560,000
    ushort_t* esrc   = (ushort_t*)(ws + 7760016);         //  2,560,000
    ushort_t* Wt     = (ushort_t*)(ws + 10320016);        //    208,896
    uint_t*   gmaxu  = (uint_t*)(ws + 10528912);          //         12
    ushort_t* Wu     = (ushort_t*)(ws + 10528928);        //    196,608 (16B aligned)

    zero_kernel<<<(NODES_REAL + 255) / 256, 256, 0, stream>>>(counts, gmaxu);
    rank_kernel<<<(Eh + 255) / 256, 256, 0, stream>>>(ei, counts, rank16, Eh);
    scan_kernel<<<1, 1024, 0, stream>>>(counts, offs);
    scatter_det<<<(Eh + 255) / 256, 256, 0, stream>>>(ei, offs, rank16, esrc, Eh);
    wsplit_kernel<<<24, 256, 0, stream>>>(Ws, Wt, Wu);

    // rows >= 5000: fused 3-layer MLP, one HBM pass
    mlp3_kernel<<<(NODES_TOTAL - NODES_REAL + 127) / 128, 256, 0, stream>>>(x, Wu, bs, out);

    // rows < 5000: per-layer GAT pipeline
    for (int l = 0; l < 3; ++l) {
        const float* hin = (l == 0) ? x : bufS;
        float* hout = (l == 2) ? out : bufS;
        gsmall_kernel<<<(NODES_REAL + 127) / 128, 256, 0, stream>>>(
            hin, Wt + (size_t)l * WT_L, as_ + l * D, ad_ + l * D, h2, sv, dv, gmaxu + l);
        agg_kernel<<<(NODES_REAL + 3) / 4, 256, 0, stream>>>(
            h2, sv, dv, offs, esrc, bs + l * D, hout, gmaxu + l);
    }
}

// Round 2
// 517.172 us; speedup vs baseline: 1.1434x; 1.1434x over previous
//
#include <hip/hip_runtime.h>
#include <math.h>

#define NODES_TOTAL 160000
#define NODES_REAL  5000
#define D 128
#define NEG 0.2f
#define KP 136                // padded k-pitch (ushorts) -> spread banks for ds_read_b128
#define HL (128 * KP)         // ushorts per hi (or lo) block = 17408
#define WT_L (2 * HL)         // ushorts per layer (hi + lo)  = 34816

typedef unsigned short ushort_t;
typedef unsigned int uint_t;
typedef __attribute__((ext_vector_type(8))) __bf16 bf16x8;
typedef __attribute__((ext_vector_type(4))) float f32x4;
union BF8 { bf16x8 v; ushort_t u[8]; };

__device__ __forceinline__ void split2(float x, ushort_t& hi, ushort_t& lo) {
    unsigned u = __float_as_uint(x);
    hi = (ushort_t)(u >> 16);
    float hif = __uint_as_float(u & 0xffff0000u);
    lo = (ushort_t)(__float_as_uint(x - hif) >> 16);
}
__device__ __forceinline__ uint_t encmax(float f) {
    uint_t b = __float_as_uint(f);
    return b ^ ((uint_t)((int)b >> 31) | 0x80000000u);
}
__device__ __forceinline__ float decmax(uint_t u) {
    uint_t b = (u & 0x80000000u) ? (u ^ 0x80000000u) : ~u;
    return __uint_as_float(b);
}

// ---------------- CSR build ----------------------------------------------------
__global__ void zero_kernel(int* counts, uint_t* gmaxu) {
    int i = blockIdx.x * blockDim.x + threadIdx.x;
    if (i < NODES_REAL) counts[i] = 0;
    if (i < 3) gmaxu[i] = 0u;
}

__global__ void rank_kernel(const int* __restrict__ ei, int* __restrict__ counts,
                            ushort_t* __restrict__ rank16, int Eh) {
    int e = blockIdx.x * blockDim.x + threadIdx.x;
    if (e < Eh) {
        int d = ei[Eh + e];
        int r = atomicAdd(&counts[d], 1);
        rank16[e] = (ushort_t)r;
    }
}

__global__ void scan_kernel(const int* __restrict__ counts, int* __restrict__ offs) {
    __shared__ int sd[1024];
    int t = threadIdx.x;
    int pre[5]; int sum = 0;
    #pragma unroll
    for (int u = 0; u < 5; ++u) {
        int idx = t * 5 + u;
        int c = (idx < NODES_REAL) ? counts[idx] : 0;
        pre[u] = sum; sum += c;
    }
    sd[t] = sum;
    __syncthreads();
    int run = sum;
    for (int o = 1; o < 1024; o <<= 1) {
        int v = (t >= o) ? sd[t - o] : 0;
        __syncthreads();
        sd[t] += v;
        __syncthreads();
    }
    int excl = sd[t] - run;
    #pragma unroll
    for (int u = 0; u < 5; ++u) {
        int idx = t * 5 + u;
        if (idx < NODES_REAL) offs[idx] = excl + pre[u];
    }
    if (t == 1023) offs[NODES_REAL] = excl + run;
}

// deterministic scatter, u16 payload (src < 5000)
__global__ void scatter_det(const int* __restrict__ ei, const int* __restrict__ offs,
                            const ushort_t* __restrict__ rank16, ushort_t* __restrict__ esrc,
                            int Eh) {
    int e = blockIdx.x * blockDim.x + threadIdx.x;
    if (e < Eh) {
        int s = ei[e];
        int d = ei[Eh + e];
        esrc[offs[d] + (int)rank16[e]] = (ushort_t)s;
    }
}

// ---------------- W split+transpose into padded layout [n][KP] hi then lo ------
__global__ void wsplit_kernel(const float* __restrict__ Ws, ushort_t* __restrict__ Wt) {
    int l  = blockIdx.x >> 3;
    int n  = (blockIdx.x & 7) * 16 + (threadIdx.x >> 4);
    int k0 = (threadIdx.x & 15) * 8;
    const float* src = Ws + (size_t)l * D * D;
    union { ushort_t u[8]; uint4 v; } hi, lo;
    #pragma unroll
    for (int j = 0; j < 8; ++j) split2(src[(size_t)(k0 + j) * D + n], hi.u[j], lo.u[j]);
    ushort_t* dhi = Wt + (size_t)l * WT_L + n * KP + k0;
    *(uint4*)dhi = hi.v;
    *(uint4*)(dhi + HL) = lo.v;
}

// ---------------- fused 3-layer MLP for rows [5000,160000) ---------------------
// W in LDS (69.6KB) + pair-shared fp32 scratch (67.6KB) = 137KB, 1 block/CU.
// 512 threads = 8 waves -> 2 waves/SIMD (vs round-0's 1/SIMD at same LDS).
// Wave pairs share one 32-row tile; each wave computes 4 of the 8 col-tiles.
// All A-fragments are hoisted to registers between the two per-layer barriers,
// so the pair-shared scr has no read/write race within a layer.
__global__ __launch_bounds__(512)
void mlp3_kernel(const float* __restrict__ x, const ushort_t* __restrict__ Wt,
                 const float* __restrict__ bs, float* __restrict__ out) {
    __shared__ ushort_t Wl[WT_L];          // 69632 B
    __shared__ float scr[4][2][16][132];   // 67584 B
    int tid = threadIdx.x;
    int w = tid >> 6, lane = tid & 63, q = lane >> 4, m16 = lane & 15;
    int p = w >> 1, h = w & 1;             // pair index, column-half index
    int row0 = NODES_REAL + blockIdx.x * 128 + p * 32;

    // layer-0 A prefetch into registers (overlaps first W staging)
    float4 xa[2][4][2];
    #pragma unroll
    for (int rt = 0; rt < 2; ++rt) {
        int r = row0 + rt * 16 + m16;
        if (r > NODES_TOTAL - 1) r = NODES_TOTAL - 1;
        #pragma unroll
        for (int kc = 0; kc < 4; ++kc) {
            const float* gp = x + (size_t)r * D + kc * 32 + q * 8;
            xa[rt][kc][0] = *(const float4*)gp;
            xa[rt][kc][1] = *(const float4*)(gp + 4);
        }
    }

    f32x4 acc[2][4];
    #pragma unroll
    for (int l = 0; l < 3; ++l) {
        __syncthreads();   // prior layer's B-reads + A-reg-loads done before overwrite
        {
            const uint4* gw = (const uint4*)(Wt + (size_t)l * WT_L);
            uint4* lw = (uint4*)Wl;
            #pragma unroll
            for (int r = 0; r < 8; ++r) lw[r * 512 + tid] = gw[r * 512 + tid];
            if (tid < 256) lw[4096 + tid] = gw[4096 + tid];
        }
        // hoist A for this layer into registers (l>0: from pair-shared scr).
        // Placed before the barrier: overlaps W staging; completes before any
        // wave can overwrite scr (its scr writes come after this barrier).
        if (l > 0) {
            #pragma unroll
            for (int rt = 0; rt < 2; ++rt)
                #pragma unroll
                for (int kc = 0; kc < 4; ++kc) {
                    const float* sp = &scr[p][rt][m16][kc * 32 + q * 8];
                    xa[rt][kc][0] = *(const float4*)sp;
                    xa[rt][kc][1] = *(const float4*)(sp + 4);
                }
        }
        __syncthreads();

        #pragma unroll
        for (int rt = 0; rt < 2; ++rt)
            #pragma unroll
            for (int ct = 0; ct < 4; ++ct) acc[rt][ct] = (f32x4){0.f, 0.f, 0.f, 0.f};

        #pragma unroll
        for (int kc = 0; kc < 4; ++kc) {
            BF8 ahi[2], alo[2];
            #pragma unroll
            for (int rt = 0; rt < 2; ++rt) {
                float4 v0 = xa[rt][kc][0], v1 = xa[rt][kc][1];
                float xv[8] = {v0.x, v0.y, v0.z, v0.w, v1.x, v1.y, v1.z, v1.w};
                #pragma unroll
                for (int j = 0; j < 8; ++j) split2(xv[j], ahi[rt].u[j], alo[rt].u[j]);
            }
            #pragma unroll
            for (int ct = 0; ct < 4; ++ct) {
                int ctg = h * 4 + ct;
                const ushort_t* bp = Wl + (ctg * 16 + m16) * KP + kc * 32 + q * 8;
                bf16x8 bhi = *(const bf16x8*)bp;
                bf16x8 blo = *(const bf16x8*)(bp + HL);
                #pragma unroll
                for (int rt = 0; rt < 2; ++rt) {
                    acc[rt][ct] = __builtin_amdgcn_mfma_f32_16x16x32_bf16(ahi[rt].v, bhi, acc[rt][ct], 0, 0, 0);
                    acc[rt][ct] = __builtin_amdgcn_mfma_f32_16x16x32_bf16(ahi[rt].v, blo, acc[rt][ct], 0, 0, 0);
                    acc[rt][ct] = __builtin_amdgcn_mfma_f32_16x16x32_bf16(alo[rt].v, bhi, acc[rt][ct], 0, 0, 0);
                }
            }
        }
        // relu(h2 + b) -> pair-shared scratch; the two waves of a pair write
        // disjoint column halves of the same rows. Reads happen next layer
        // after a barrier.
        float bv[4];
        #pragma unroll
        for (int ct = 0; ct < 4; ++ct) bv[ct] = bs[l * D + (h * 4 + ct) * 16 + m16];
        #pragma unroll
        for (int rt = 0; rt < 2; ++rt)
            #pragma unroll
            for (int ct = 0; ct < 4; ++ct)
                #pragma unroll
                for (int reg = 0; reg < 4; ++reg)
                    scr[p][rt][q * 4 + reg][(h * 4 + ct) * 16 + m16] =
                        fmaxf(acc[rt][ct][reg] + bv[ct], 0.f);
    }
    __syncthreads();   // partner's final scr writes visible for epilogue
    // coalesced epilogue: each wave streams its 16 rows (rt = h) x 128 cols,
    // consecutive lanes -> consecutive 16B -> 1KB per store instruction.
    #pragma unroll
    for (int i = 0; i < 8; ++i) {
        int rowl = i * 2 + (lane >> 5);          // 0..15
        int grow = row0 + h * 16 + rowl;
        float4 v = *(const float4*)&scr[p][h][rowl][(lane & 31) * 4];
        if (grow < NODES_TOTAL)
            *(float4*)&out[(size_t)grow * D + (lane & 31) * 4] = v;
    }
}

// ---------------- small GEMM (rows<5000) + fused scores + per-layer max --------
__global__ __launch_bounds__(256)
void gsmall_kernel(const float* __restrict__ hin, const ushort_t* __restrict__ Wlg,
                   const float* __restrict__ a_s, const float* __restrict__ a_d,
                   float* __restrict__ h2, float* __restrict__ sv, float* __restrict__ dv,
                   uint_t* __restrict__ gmaxu) {
    __shared__ ushort_t Wl[WT_L];
    int tid = threadIdx.x;
    {
        const uint4* gw = (const uint4*)Wlg;
        uint4* lw = (uint4*)Wl;
        #pragma unroll
        for (int r = 0; r < 17; ++r) lw[r * 256 + tid] = gw[r * 256 + tid];
    }
    int w = tid >> 6, lane = tid & 63, q = lane >> 4, m16 = lane & 15;
    int row0 = blockIdx.x * 128 + w * 32;
    f32x4 acc[2][8];
    #pragma unroll
    for (int rt = 0; rt < 2; ++rt)
        #pragma unroll
        for (int ct = 0; ct < 8; ++ct) acc[rt][ct] = (f32x4){0.f, 0.f, 0.f, 0.f};
    // prefetch A while W stages
    float4 xa[2][4][2];
    #pragma unroll
    for (int rt = 0; rt < 2; ++rt) {
        int r = row0 + rt * 16 + m16;
        if (r > NODES_REAL - 1) r = NODES_REAL - 1;
        #pragma unroll
        for (int kc = 0; kc < 4; ++kc) {
            const float* gp = hin + (size_t)r * D + kc * 32 + q * 8;
            xa[rt][kc][0] = *(const float4*)gp;
            xa[rt][kc][1] = *(const float4*)(gp + 4);
        }
    }
    __syncthreads();
    #pragma unroll
    for (int kc = 0; kc < 4; ++kc) {
        BF8 ahi[2], alo[2];
        #pragma unroll
        for (int rt = 0; rt < 2; ++rt) {
            float4 v0 = xa[rt][kc][0], v1 = xa[rt][kc][1];
            float xv[8] = {v0.x, v0.y, v0.z, v0.w, v1.x, v1.y, v1.z, v1.w};
            #pragma unroll
            for (int j = 0; j < 8; ++j) split2(xv[j], ahi[rt].u[j], alo[rt].u[j]);
        }
        #pragma unroll
        for (int ct = 0; ct < 8; ++ct) {
            const ushort_t* bp = Wl + (ct * 16 + m16) * KP + kc * 32 + q * 8;
            bf16x8 bhi = *(const bf16x8*)bp;
            bf16x8 blo = *(const bf16x8*)(bp + HL);
            #pragma unroll
            for (int rt = 0; rt < 2; ++rt) {
                acc[rt][ct] = __builtin_amdgcn_mfma_f32_16x16x32_bf16(ahi[rt].v, bhi, acc[rt][ct], 0, 0, 0);
                acc[rt][ct] = __builtin_amdgcn_mfma_f32_16x16x32_bf16(ahi[rt].v, blo, acc[rt][ct], 0, 0, 0);
                acc[rt][ct] = __builtin_amdgcn_mfma_f32_16x16x32_bf16(alo[rt].v, bhi, acc[rt][ct], 0, 0, 0);
            }
        }
    }
    #pragma unroll
    for (int rt = 0; rt < 2; ++rt)
        #pragma unroll
        for (int reg = 0; reg < 4; ++reg) {
            int grow = row0 + rt * 16 + q * 4 + reg;
            if (grow < NODES_REAL) {
                #pragma unroll
                for (int ct = 0; ct < 8; ++ct)
                    h2[(size_t)grow * D + ct * 16 + m16] = acc[rt][ct][reg];
            }
        }
    float asv[8], adv[8];
    #pragma unroll
    for (int ct = 0; ct < 8; ++ct) { asv[ct] = a_s[ct * 16 + m16]; adv[ct] = a_d[ct * 16 + m16]; }
    #pragma unroll
    for (int rt = 0; rt < 2; ++rt)
        #pragma unroll
        for (int reg = 0; reg < 4; ++reg) {
            float ps = 0.f, pd = 0.f;
            #pragma unroll
            for (int ct = 0; ct < 8; ++ct) {
                float v = acc[rt][ct][reg];
                ps += v * asv[ct]; pd += v * adv[ct];
            }
            #pragma unroll
            for (int o = 1; o < 16; o <<= 1) { ps += __shfl_xor(ps, o); pd += __shfl_xor(pd, o); }
            int grow = row0 + rt * 16 + q * 4 + reg;
            if (m16 == 0 && grow < NODES_REAL) {
                sv[grow] = ps; dv[grow] = pd;
                atomicMax(gmaxu, encmax(ps));
            }
        }
}

// ---------------- aggregation: one wave per dst, global-bound softmax ----------
__global__ __launch_bounds__(256)
void agg_kernel(const float* __restrict__ h2, const float* __restrict__ sv,
                const float* __restrict__ dv, const int* __restrict__ offs,
                const ushort_t* __restrict__ esrc, const float* __restrict__ bias,
                float* __restrict__ out, const uint_t* __restrict__ gmaxu) {
    int w = threadIdx.x >> 6, lane = threadIdx.x & 63;
    int i = blockIdx.x * 4 + w;
    int start = offs[i], end = offs[i + 1];
    float d_i = dv[i];
    float gm = decmax(*gmaxu) + d_i;       // upper bound on every incoming score
    float m = gm > 0.f ? gm : NEG * gm;    // leaky_relu monotone -> exact shift
    float ax = 0.f, ay = 0.f, ax1 = 0.f, ay1 = 0.f, exs = 0.f;
    for (int base = start; base < end; base += 64) {
        int cnt = min(64, end - base);
        int srci = (lane < cnt) ? (int)esrc[base + lane] : 0;
        float sc = sv[srci] + d_i;
        sc = sc > 0.f ? sc : NEG * sc;
        float ex = (lane < cnt) ? __expf(sc - m) : 0.f;
        exs += ex;
        if (cnt == 64) {
            #pragma unroll 4
            for (int j = 0; j < 64; j += 2) {   // 2 independent fmac chains
                int   s0 = __shfl(srci, j),     s1 = __shfl(srci, j + 1);
                float e0 = __shfl(ex, j),       e1 = __shfl(ex, j + 1);
                float2 h0 = *(const float2*)&h2[(size_t)s0 * D + 2 * lane];
                float2 h1 = *(const float2*)&h2[(size_t)s1 * D + 2 * lane];
                ax  += e0 * h0.x; ay  += e0 * h0.y;
                ax1 += e1 * h1.x; ay1 += e1 * h1.y;
            }
        } else {
            for (int j = 0; j < cnt; ++j) {
                int   src = __shfl(srci, j);
                float e   = __shfl(ex, j);
                float2 hv = *(const float2*)&h2[(size_t)src * D + 2 * lane];
                ax += e * hv.x; ay += e * hv.y;
            }
        }
    }
    ax += ax1; ay += ay1;
    float scf = sv[i] + d_i; scf = scf > 0.f ? scf : NEG * scf;
    float exf = __expf(scf - m);
    float2 hv = *(const float2*)&h2[(size_t)i * D + 2 * lane];
    ax += exf * hv.x; ay += exf * hv.y;
    #pragma unroll
    for (int o = 1; o < 64; o <<= 1) exs += __shfl_xor(exs, o);
    float rd = 1.f / (exs + exf);
    float2 b2 = *(const float2*)&bias[2 * lane];
    float2 o2 = make_float2(fmaxf(ax * rd + b2.x, 0.f), fmaxf(ay * rd + b2.y, 0.f));
    *(float2*)&out[(size_t)i * D + 2 * lane] = o2;
}

// ---------------- launcher -----------------------------------------------------
extern "C" void kernel_launch(void* const* d_in, const int* in_sizes, int n_in,
                              void* d_out, int out_size, void* d_ws, size_t ws_size,
                              hipStream_t stream) {
    const float* x   = (const float*)d_in[0];
    const int*   ei  = (const int*)d_in[1];
    const float* Ws  = (const float*)d_in[2];
    const float* as_ = (const float*)d_in[3];
    const float* ad_ = (const float*)d_in[4];
    const float* bs  = (const float*)d_in[5];
    float* out = (float*)d_out;
    int Eh = in_sizes[1] / 2;                    // 1,280,000

    char* ws = (char*)d_ws;
    float*    h2     = (float*)ws;                        //  2,560,000
    float*    bufS   = (float*)(ws + 2560000);            //  2,560,000
    float*    sv     = (float*)(ws + 5120000);            //     20,000
    float*    dv     = (float*)(ws + 5140000);            //     20,000
    int*      counts = (int*)  (ws + 5160000);            //     20,000
    int*      offs   = (int*)  (ws + 5180000);            //     20,016
    ushort_t* rank16 = (ushort_t*)(ws + 5200016);         //  2,560,000
    ushort_t* esrc   = (ushort_t*)(ws + 7760016);         //  2,560,000
    ushort_t* Wt     = (ushort_t*)(ws + 10320016);        //    208,896
    uint_t*   gmaxu  = (uint_t*)(ws + 10528912);          //         12

    zero_kernel<<<(NODES_REAL + 255) / 256, 256, 0, stream>>>(counts, gmaxu);
    rank_kernel<<<(Eh + 255) / 256, 256, 0, stream>>>(ei, counts, rank16, Eh);
    scan_kernel<<<1, 1024, 0, stream>>>(counts, offs);
    scatter_det<<<(Eh + 255) / 256, 256, 0, stream>>>(ei, offs, rank16, esrc, Eh);
    wsplit_kernel<<<24, 256, 0, stream>>>(Ws, Wt);

    // rows >= 5000: fused 3-layer MLP, one HBM pass
    mlp3_kernel<<<(NODES_TOTAL - NODES_REAL + 127) / 128, 512, 0, stream>>>(x, Wt, bs, out);

    // rows < 5000: per-layer GAT pipeline
    for (int l = 0; l < 3; ++l) {
        const float* hin = (l == 0) ? x : bufS;
        float* hout = (l == 2) ? out : bufS;
        gsmall_kernel<<<(NODES_REAL + 127) / 128, 256, 0, stream>>>(
            hin, Wt + (size_t)l * WT_L, as_ + l * D, ad_ + l * D, h2, sv, dv, gmaxu + l);
        agg_kernel<<<(NODES_REAL + 3) / 4, 256, 0, stream>>>(
            h2, sv, dv, offs, esrc, bs + l * D, hout, gmaxu + l);
    }
}

// Round 3
// 515.007 us; speedup vs baseline: 1.1482x; 1.0042x over previous
//
#include <hip/hip_runtime.h>
#include <math.h>

#define NODES_TOTAL 160000
#define NODES_REAL  5000
#define D 128
#define NEG 0.2f
#define KP2 128               // unpadded k-pitch (ushorts); conflicts killed by XOR swizzle
#define HL2 (128 * KP2)       // ushorts per hi (or lo) block = 16384
#define WT2_L (2 * HL2)       // ushorts per layer (hi + lo)  = 32768 (64 KB)

typedef unsigned short ushort_t;
typedef unsigned int uint_t;
typedef __attribute__((ext_vector_type(8))) __bf16 bf16x8;
typedef __attribute__((ext_vector_type(4))) float f32x4;
union BF8 { bf16x8 v; ushort_t u[8]; };

__device__ __forceinline__ void split2(float x, ushort_t& hi, ushort_t& lo) {
    unsigned u = __float_as_uint(x);
    hi = (ushort_t)(u >> 16);
    float hif = __uint_as_float(u & 0xffff0000u);
    lo = (ushort_t)(__float_as_uint(x - hif) >> 16);
}
__device__ __forceinline__ uint_t encmax(float f) {
    uint_t b = __float_as_uint(f);
    return b ^ ((uint_t)((int)b >> 31) | 0x80000000u);
}
__device__ __forceinline__ float decmax(uint_t u) {
    uint_t b = (u & 0x80000000u) ? (u ^ 0x80000000u) : ~u;
    return __uint_as_float(b);
}

// ---------------- CSR build ----------------------------------------------------
__global__ void zero_kernel(int* counts, uint_t* gmaxu) {
    int i = blockIdx.x * blockDim.x + threadIdx.x;
    if (i < NODES_REAL) counts[i] = 0;
    if (i < 3) gmaxu[i] = 0u;
}

__global__ void rank_kernel(const int* __restrict__ ei, int* __restrict__ counts,
                            ushort_t* __restrict__ rank16, int Eh) {
    int e = blockIdx.x * blockDim.x + threadIdx.x;
    if (e < Eh) {
        int d = ei[Eh + e];
        int r = atomicAdd(&counts[d], 1);
        rank16[e] = (ushort_t)r;
    }
}

__global__ void scan_kernel(const int* __restrict__ counts, int* __restrict__ offs) {
    __shared__ int sd[1024];
    int t = threadIdx.x;
    int pre[5]; int sum = 0;
    #pragma unroll
    for (int u = 0; u < 5; ++u) {
        int idx = t * 5 + u;
        int c = (idx < NODES_REAL) ? counts[idx] : 0;
        pre[u] = sum; sum += c;
    }
    sd[t] = sum;
    __syncthreads();
    int run = sum;
    for (int o = 1; o < 1024; o <<= 1) {
        int v = (t >= o) ? sd[t - o] : 0;
        __syncthreads();
        sd[t] += v;
        __syncthreads();
    }
    int excl = sd[t] - run;
    #pragma unroll
    for (int u = 0; u < 5; ++u) {
        int idx = t * 5 + u;
        if (idx < NODES_REAL) offs[idx] = excl + pre[u];
    }
    if (t == 1023) offs[NODES_REAL] = excl + run;
}

// deterministic scatter, u16 payload (src < 5000)
__global__ void scatter_det(const int* __restrict__ ei, const int* __restrict__ offs,
                            const ushort_t* __restrict__ rank16, ushort_t* __restrict__ esrc,
                            int Eh) {
    int e = blockIdx.x * blockDim.x + threadIdx.x;
    if (e < Eh) {
        int s = ei[e];
        int d = ei[Eh + e];
        esrc[offs[d] + (int)rank16[e]] = (ushort_t)s;
    }
}

// ---------------- W split+transpose, PRE-SWIZZLED in global -------------------
// Layout: layer l, row n (out-col), col8 = k/8: ushort index
//   l*WT2_L + n*128 + (col8 ^ (n&15))*8   (hi; lo at +HL2)
// Staging to LDS is a LINEAR copy; readers apply the same XOR. A 16-lane read
// phase (fixed q,kc,ct) then covers 16B slots 2-way max -> conflict-free.
__global__ void wsplit_kernel(const float* __restrict__ Ws, ushort_t* __restrict__ Wt) {
    int l  = blockIdx.x >> 3;
    int n  = (blockIdx.x & 7) * 16 + (threadIdx.x >> 4);
    int c8 = threadIdx.x & 15;
    int k0 = c8 * 8;
    const float* src = Ws + (size_t)l * D * D;
    union { ushort_t u[8]; uint4 v; } hi, lo;
    #pragma unroll
    for (int j = 0; j < 8; ++j) split2(src[(size_t)(k0 + j) * D + n], hi.u[j], lo.u[j]);
    int c8s = c8 ^ (n & 15);
    ushort_t* dhi = Wt + (size_t)l * WT2_L + n * KP2 + c8s * 8;
    *(uint4*)dhi = hi.v;
    *(uint4*)(dhi + HL2) = lo.v;
}

// ---------------- fused 3-layer MLP for rows [5000,160000) ---------------------
// W in LDS (64KB, swizzled layout) + pair-shared fp32 scratch (67.6KB) = 131.6KB,
// 1 block/CU, 8 waves (2/SIMD). Per layer: A pre-split ONCE into bf16 hi/lo regs,
// then the kc loop is a pure ds_read/MFMA 2-deep software pipeline: B(kc+1) loads
// are issued before kc's MFMA burst, so ds latency hides under MFMA.
__global__ __launch_bounds__(512)
void mlp3_kernel(const float* __restrict__ x, const ushort_t* __restrict__ Wt,
                 const float* __restrict__ bs, float* __restrict__ out) {
    __shared__ ushort_t Wl[WT2_L];         // 65536 B
    __shared__ float scr[4][2][16][132];   // 67584 B
    int tid = threadIdx.x;
    int w = tid >> 6, lane = tid & 63, q = lane >> 4, m16 = lane & 15;
    int p = w >> 1, h = w & 1;             // pair index, column-half index
    int row0 = NODES_REAL + blockIdx.x * 128 + p * 32;

    // layer-0 A prefetch into registers (overlaps first W staging)
    float4 xa[2][4][2];
    #pragma unroll
    for (int rt = 0; rt < 2; ++rt) {
        int r = row0 + rt * 16 + m16;
        if (r > NODES_TOTAL - 1) r = NODES_TOTAL - 1;
        #pragma unroll
        for (int kc = 0; kc < 4; ++kc) {
            const float* gp = x + (size_t)r * D + kc * 32 + q * 8;
            xa[rt][kc][0] = *(const float4*)gp;
            xa[rt][kc][1] = *(const float4*)(gp + 4);
        }
    }

    f32x4 acc[2][4];
    #pragma unroll
    for (int l = 0; l < 3; ++l) {
        __syncthreads();   // prior layer's B/scr reads done before overwrite
        {
            const uint4* gw = (const uint4*)(Wt + (size_t)l * WT2_L);
            uint4* lw = (uint4*)Wl;
            #pragma unroll
            for (int r = 0; r < 8; ++r) lw[r * 512 + tid] = gw[r * 512 + tid];
        }
        // hoist A for this layer into registers (l>0: from pair-shared scr);
        // overlaps W staging, completes before any wave's scr overwrite.
        if (l > 0) {
            #pragma unroll
            for (int rt = 0; rt < 2; ++rt)
                #pragma unroll
                for (int kc = 0; kc < 4; ++kc) {
                    const float* sp = &scr[p][rt][m16][kc * 32 + q * 8];
                    xa[rt][kc][0] = *(const float4*)sp;
                    xa[rt][kc][1] = *(const float4*)(sp + 4);
                }
        }
        __syncthreads();

        // pre-split all A into bf16 hi/lo registers (pure VALU, no loads after)
        BF8 ahi[2][4], alo[2][4];
        #pragma unroll
        for (int rt = 0; rt < 2; ++rt)
            #pragma unroll
            for (int kc = 0; kc < 4; ++kc) {
                float4 v0 = xa[rt][kc][0], v1 = xa[rt][kc][1];
                float xv[8] = {v0.x, v0.y, v0.z, v0.w, v1.x, v1.y, v1.z, v1.w};
                #pragma unroll
                for (int j = 0; j < 8; ++j) split2(xv[j], ahi[rt][kc].u[j], alo[rt][kc].u[j]);
            }

        #pragma unroll
        for (int rt = 0; rt < 2; ++rt)
            #pragma unroll
            for (int ct = 0; ct < 4; ++ct) acc[rt][ct] = (f32x4){0.f, 0.f, 0.f, 0.f};

        // B base: row = (h*4+ct)*16 + m16 -> ushort off (h*4+ct)*2048 + m16*128
        const ushort_t* wbase = Wl + (h * 4) * (16 * KP2) + m16 * KP2;

        // prime kc=0
        bf16x8 bh[2][4], bl[2][4];
        #pragma unroll
        for (int ct = 0; ct < 4; ++ct) {
            const ushort_t* bp = wbase + ct * (16 * KP2) + (((0 * 4 + q) ^ m16) * 8);
            bh[0][ct] = *(const bf16x8*)bp;
            bl[0][ct] = *(const bf16x8*)(bp + HL2);
        }
        #pragma unroll
        for (int kc = 0; kc < 4; ++kc) {
            int cur = kc & 1, nxt = cur ^ 1;           // static after unroll
            if (kc < 3) {
                #pragma unroll
                for (int ct = 0; ct < 4; ++ct) {
                    const ushort_t* bp = wbase + ct * (16 * KP2) + ((((kc + 1) * 4 + q) ^ m16) * 8);
                    bh[nxt][ct] = *(const bf16x8*)bp;
                    bl[nxt][ct] = *(const bf16x8*)(bp + HL2);
                }
            }
            #pragma unroll
            for (int ct = 0; ct < 4; ++ct)
                #pragma unroll
                for (int rt = 0; rt < 2; ++rt) {
                    acc[rt][ct] = __builtin_amdgcn_mfma_f32_16x16x32_bf16(ahi[rt][kc].v, bh[cur][ct], acc[rt][ct], 0, 0, 0);
                    acc[rt][ct] = __builtin_amdgcn_mfma_f32_16x16x32_bf16(ahi[rt][kc].v, bl[cur][ct], acc[rt][ct], 0, 0, 0);
                    acc[rt][ct] = __builtin_amdgcn_mfma_f32_16x16x32_bf16(alo[rt][kc].v, bh[cur][ct], acc[rt][ct], 0, 0, 0);
                }
        }
        // relu(h2 + b) -> pair-shared scratch (disjoint col halves per wave)
        float bv[4];
        #pragma unroll
        for (int ct = 0; ct < 4; ++ct) bv[ct] = bs[l * D + (h * 4 + ct) * 16 + m16];
        #pragma unroll
        for (int rt = 0; rt < 2; ++rt)
            #pragma unroll
            for (int ct = 0; ct < 4; ++ct)
                #pragma unroll
                for (int reg = 0; reg < 4; ++reg)
                    scr[p][rt][q * 4 + reg][(h * 4 + ct) * 16 + m16] =
                        fmaxf(acc[rt][ct][reg] + bv[ct], 0.f);
    }
    __syncthreads();   // partner's final scr writes visible for epilogue
    // coalesced epilogue: each wave streams its 16 rows (rt = h) x 128 cols
    #pragma unroll
    for (int i = 0; i < 8; ++i) {
        int rowl = i * 2 + (lane >> 5);          // 0..15
        int grow = row0 + h * 16 + rowl;
        float4 v = *(const float4*)&scr[p][h][rowl][(lane & 31) * 4];
        if (grow < NODES_TOTAL)
            *(float4*)&out[(size_t)grow * D + (lane & 31) * 4] = v;
    }
}

// ---------------- small GEMM (rows<5000) + fused scores + per-layer max --------
__global__ __launch_bounds__(256)
void gsmall_kernel(const float* __restrict__ hin, const ushort_t* __restrict__ Wlg,
                   const float* __restrict__ a_s, const float* __restrict__ a_d,
                   float* __restrict__ h2, float* __restrict__ sv, float* __restrict__ dv,
                   uint_t* __restrict__ gmaxu) {
    __shared__ ushort_t Wl[WT2_L];         // 64 KB -> 2 blocks/CU
    int tid = threadIdx.x;
    {
        const uint4* gw = (const uint4*)Wlg;
        uint4* lw = (uint4*)Wl;
        #pragma unroll
        for (int r = 0; r < 16; ++r) lw[r * 256 + tid] = gw[r * 256 + tid];
    }
    int w = tid >> 6, lane = tid & 63, q = lane >> 4, m16 = lane & 15;
    int row0 = blockIdx.x * 128 + w * 32;
    f32x4 acc[2][8];
    #pragma unroll
    for (int rt = 0; rt < 2; ++rt)
        #pragma unroll
        for (int ct = 0; ct < 8; ++ct) acc[rt][ct] = (f32x4){0.f, 0.f, 0.f, 0.f};
    // prefetch A while W stages
    float4 xa[2][4][2];
    #pragma unroll
    for (int rt = 0; rt < 2; ++rt) {
        int r = row0 + rt * 16 + m16;
        if (r > NODES_REAL - 1) r = NODES_REAL - 1;
        #pragma unroll
        for (int kc = 0; kc < 4; ++kc) {
            const float* gp = hin + (size_t)r * D + kc * 32 + q * 8;
            xa[rt][kc][0] = *(const float4*)gp;
            xa[rt][kc][1] = *(const float4*)(gp + 4);
        }
    }
    __syncthreads();
    #pragma unroll
    for (int kc = 0; kc < 4; ++kc) {
        BF8 ahi[2], alo[2];
        #pragma unroll
        for (int rt = 0; rt < 2; ++rt) {
            float4 v0 = xa[rt][kc][0], v1 = xa[rt][kc][1];
            float xv[8] = {v0.x, v0.y, v0.z, v0.w, v1.x, v1.y, v1.z, v1.w};
            #pragma unroll
            for (int j = 0; j < 8; ++j) split2(xv[j], ahi[rt].u[j], alo[rt].u[j]);
        }
        #pragma unroll
        for (int ct = 0; ct < 8; ++ct) {
            const ushort_t* bp = Wl + (ct * 16 + m16) * KP2 + (((kc * 4 + q) ^ m16) * 8);
            bf16x8 bhi = *(const bf16x8*)bp;
            bf16x8 blo = *(const bf16x8*)(bp + HL2);
            #pragma unroll
            for (int rt = 0; rt < 2; ++rt) {
                acc[rt][ct] = __builtin_amdgcn_mfma_f32_16x16x32_bf16(ahi[rt].v, bhi, acc[rt][ct], 0, 0, 0);
                acc[rt][ct] = __builtin_amdgcn_mfma_f32_16x16x32_bf16(ahi[rt].v, blo, acc[rt][ct], 0, 0, 0);
                acc[rt][ct] = __builtin_amdgcn_mfma_f32_16x16x32_bf16(alo[rt].v, bhi, acc[rt][ct], 0, 0, 0);
            }
        }
    }
    #pragma unroll
    for (int rt = 0; rt < 2; ++rt)
        #pragma unroll
        for (int reg = 0; reg < 4; ++reg) {
            int grow = row0 + rt * 16 + q * 4 + reg;
            if (grow < NODES_REAL) {
                #pragma unroll
                for (int ct = 0; ct < 8; ++ct)
                    h2[(size_t)grow * D + ct * 16 + m16] = acc[rt][ct][reg];
            }
        }
    float asv[8], adv[8];
    #pragma unroll
    for (int ct = 0; ct < 8; ++ct) { asv[ct] = a_s[ct * 16 + m16]; adv[ct] = a_d[ct * 16 + m16]; }
    #pragma unroll
    for (int rt = 0; rt < 2; ++rt)
        #pragma unroll
        for (int reg = 0; reg < 4; ++reg) {
            float ps = 0.f, pd = 0.f;
            #pragma unroll
            for (int ct = 0; ct < 8; ++ct) {
                float v = acc[rt][ct][reg];
                ps += v * asv[ct]; pd += v * adv[ct];
            }
            #pragma unroll
            for (int o = 1; o < 16; o <<= 1) { ps += __shfl_xor(ps, o); pd += __shfl_xor(pd, o); }
            int grow = row0 + rt * 16 + q * 4 + reg;
            if (m16 == 0 && grow < NODES_REAL) {
                sv[grow] = ps; dv[grow] = pd;
                atomicMax(gmaxu, encmax(ps));
            }
        }
}

// ---------------- aggregation: one wave per dst, global-bound softmax ----------
__global__ __launch_bounds__(256)
void agg_kernel(const float* __restrict__ h2, const float* __restrict__ sv,
                const float* __restrict__ dv, const int* __restrict__ offs,
                const ushort_t* __restrict__ esrc, const float* __restrict__ bias,
                float* __restrict__ out, const uint_t* __restrict__ gmaxu) {
    int w = threadIdx.x >> 6, lane = threadIdx.x & 63;
    int i = blockIdx.x * 4 + w;
    int start = offs[i], end = offs[i + 1];
    float d_i = dv[i];
    float gm = decmax(*gmaxu) + d_i;       // upper bound on every incoming score
    float m = gm > 0.f ? gm : NEG * gm;    // leaky_relu monotone -> exact shift
    float ax = 0.f, ay = 0.f, ax1 = 0.f, ay1 = 0.f, exs = 0.f;
    for (int base = start; base < end; base += 64) {
        int cnt = min(64, end - base);
        int srci = (lane < cnt) ? (int)esrc[base + lane] : 0;
        float sc = sv[srci] + d_i;
        sc = sc > 0.f ? sc : NEG * sc;
        float ex = (lane < cnt) ? __expf(sc - m) : 0.f;
        exs += ex;
        if (cnt == 64) {
            #pragma unroll 4
            for (int j = 0; j < 64; j += 2) {   // 2 independent fmac chains
                int   s0 = __shfl(srci, j),     s1 = __shfl(srci, j + 1);
                float e0 = __shfl(ex, j),       e1 = __shfl(ex, j + 1);
                float2 h0 = *(const float2*)&h2[(size_t)s0 * D + 2 * lane];
                float2 h1 = *(const float2*)&h2[(size_t)s1 * D + 2 * lane];
                ax  += e0 * h0.x; ay  += e0 * h0.y;
                ax1 += e1 * h1.x; ay1 += e1 * h1.y;
            }
        } else {
            for (int j = 0; j < cnt; ++j) {
                int   src = __shfl(srci, j);
                float e   = __shfl(ex, j);
                float2 hv = *(const float2*)&h2[(size_t)src * D + 2 * lane];
                ax += e * hv.x; ay += e * hv.y;
            }
        }
    }
    ax += ax1; ay += ay1;
    float scf = sv[i] + d_i; scf = scf > 0.f ? scf : NEG * scf;
    float exf = __expf(scf - m);
    float2 hv = *(const float2*)&h2[(size_t)i * D + 2 * lane];
    ax += exf * hv.x; ay += exf * hv.y;
    #pragma unroll
    for (int o = 1; o < 64; o <<= 1) exs += __shfl_xor(exs, o);
    float rd = 1.f / (exs + exf);
    float2 b2 = *(const float2*)&bias[2 * lane];
    float2 o2 = make_float2(fmaxf(ax * rd + b2.x, 0.f), fmaxf(ay * rd + b2.y, 0.f));
    *(float2*)&out[(size_t)i * D + 2 * lane] = o2;
}

// ---------------- launcher -----------------------------------------------------
extern "C" void kernel_launch(void* const* d_in, const int* in_sizes, int n_in,
                              void* d_out, int out_size, void* d_ws, size_t ws_size,
                              hipStream_t stream) {
    const float* x   = (const float*)d_in[0];
    const int*   ei  = (const int*)d_in[1];
    const float* Ws  = (const float*)d_in[2];
    const float* as_ = (const float*)d_in[3];
    const float* ad_ = (const float*)d_in[4];
    const float* bs  = (const float*)d_in[5];
    float* out = (float*)d_out;
    int Eh = in_sizes[1] / 2;                    // 1,280,000

    char* ws = (char*)d_ws;
    float*    h2     = (float*)ws;                        //  2,560,000
    float*    bufS   = (float*)(ws + 2560000);            //  2,560,000
    float*    sv     = (float*)(ws + 5120000);            //     20,000
    float*    dv     = (float*)(ws + 5140000);            //     20,000
    int*      counts = (int*)  (ws + 5160000);            //     20,000
    int*      offs   = (int*)  (ws + 5180000);            //     20,016
    ushort_t* rank16 = (ushort_t*)(ws + 5200016);         //  2,560,000
    ushort_t* esrc   = (ushort_t*)(ws + 7760016);         //  2,560,000
    ushort_t* Wt     = (ushort_t*)(ws + 10320016);        //    196,608 (swizzled)
    uint_t*   gmaxu  = (uint_t*)(ws + 10528912);          //         12

    zero_kernel<<<(NODES_REAL + 255) / 256, 256, 0, stream>>>(counts, gmaxu);
    rank_kernel<<<(Eh + 255) / 256, 256, 0, stream>>>(ei, counts, rank16, Eh);
    scan_kernel<<<1, 1024, 0, stream>>>(counts, offs);
    scatter_det<<<(Eh + 255) / 256, 256, 0, stream>>>(ei, offs, rank16, esrc, Eh);
    wsplit_kernel<<<24, 256, 0, stream>>>(Ws, Wt);

    // rows >= 5000: fused 3-layer MLP, one HBM pass
    mlp3_kernel<<<(NODES_TOTAL - NODES_REAL + 127) / 128, 512, 0, stream>>>(x, Wt, bs, out);

    // rows < 5000: per-layer GAT pipeline
    for (int l = 0; l < 3; ++l) {
        const float* hin = (l == 0) ? x : bufS;
        float* hout = (l == 2) ? out : bufS;
        gsmall_kernel<<<(NODES_REAL + 127) / 128, 256, 0, stream>>>(
            hin, Wt + (size_t)l * WT2_L, as_ + l * D, ad_ + l * D, h2, sv, dv, gmaxu + l);
        agg_kernel<<<(NODES_REAL + 3) / 4, 256, 0, stream>>>(
            h2, sv, dv, offs, esrc, bs + l * D, hout, gmaxu + l);
    }
}

// Round 4
// 512.987 us; speedup vs baseline: 1.1527x; 1.0039x over previous
//
#include <hip/hip_runtime.h>
#include <math.h>

#define NODES_TOTAL 160000
#define NODES_REAL  5000
#define D 128
#define NEG 0.2f
#define KP2 128               // k-pitch (ushorts) for gsmall's swizzled LDS W
#define HL2 (128 * KP2)       // ushorts per hi (or lo) block = 16384
#define WT2_L (2 * HL2)       // ushorts per layer (hi + lo)  = 32768 (64 KB)

typedef unsigned short ushort_t;
typedef unsigned int uint_t;
typedef __attribute__((ext_vector_type(8))) __bf16 bf16x8;
typedef __attribute__((ext_vector_type(4))) float f32x4;
union BF8 { bf16x8 v; ushort_t u[8]; };

__device__ __forceinline__ void split2(float x, ushort_t& hi, ushort_t& lo) {
    unsigned u = __float_as_uint(x);
    hi = (ushort_t)(u >> 16);
    float hif = __uint_as_float(u & 0xffff0000u);
    lo = (ushort_t)(__float_as_uint(x - hif) >> 16);
}
__device__ __forceinline__ uint_t encmax(float f) {
    uint_t b = __float_as_uint(f);
    return b ^ ((uint_t)((int)b >> 31) | 0x80000000u);
}
__device__ __forceinline__ float decmax(uint_t u) {
    uint_t b = (u & 0x80000000u) ? (u ^ 0x80000000u) : ~u;
    return __uint_as_float(b);
}

// ---------------- CSR build ----------------------------------------------------
__global__ void zero_kernel(int* counts, uint_t* gmaxu) {
    int i = blockIdx.x * blockDim.x + threadIdx.x;
    if (i < NODES_REAL) counts[i] = 0;
    if (i < 3) gmaxu[i] = 0u;
}

__global__ void rank_kernel(const int* __restrict__ ei, int* __restrict__ counts,
                            ushort_t* __restrict__ rank16, int Eh) {
    int e = blockIdx.x * blockDim.x + threadIdx.x;
    if (e < Eh) {
        int d = ei[Eh + e];
        int r = atomicAdd(&counts[d], 1);
        rank16[e] = (ushort_t)r;
    }
}

__global__ void scan_kernel(const int* __restrict__ counts, int* __restrict__ offs) {
    __shared__ int sd[1024];
    int t = threadIdx.x;
    int pre[5]; int sum = 0;
    #pragma unroll
    for (int u = 0; u < 5; ++u) {
        int idx = t * 5 + u;
        int c = (idx < NODES_REAL) ? counts[idx] : 0;
        pre[u] = sum; sum += c;
    }
    sd[t] = sum;
    __syncthreads();
    int run = sum;
    for (int o = 1; o < 1024; o <<= 1) {
        int v = (t >= o) ? sd[t - o] : 0;
        __syncthreads();
        sd[t] += v;
        __syncthreads();
    }
    int excl = sd[t] - run;
    #pragma unroll
    for (int u = 0; u < 5; ++u) {
        int idx = t * 5 + u;
        if (idx < NODES_REAL) offs[idx] = excl + pre[u];
    }
    if (t == 1023) offs[NODES_REAL] = excl + run;
}

// deterministic scatter, u16 payload (src < 5000)
__global__ void scatter_det(const int* __restrict__ ei, const int* __restrict__ offs,
                            const ushort_t* __restrict__ rank16, ushort_t* __restrict__ esrc,
                            int Eh) {
    int e = blockIdx.x * blockDim.x + threadIdx.x;
    if (e < Eh) {
        int s = ei[e];
        int d = ei[Eh + e];
        esrc[offs[d] + (int)rank16[e]] = (ushort_t)s;
    }
}

// ---------------- W split+transpose -> two layouts -----------------------------
// Wt: swizzled [n][128] (gsmall LDS path, reader XORs col8 by n&15).
// Wm: fragment-major for mlp3's B-in-registers path:
//   off(l,ct,kc,hl,lane) = l*WT2_L + ((ct*4+kc)*2+hl)*512 + lane*8
//   so one wave-load of frag (ct,kc,hl) = 64 lanes x 16B = 1KB CONTIGUOUS.
__global__ void wsplit_kernel(const float* __restrict__ Ws, ushort_t* __restrict__ Wt,
                              ushort_t* __restrict__ Wm) {
    int l  = blockIdx.x >> 3;
    int n  = (blockIdx.x & 7) * 16 + (threadIdx.x >> 4);
    int c8 = threadIdx.x & 15;
    int k0 = c8 * 8;
    const float* src = Ws + (size_t)l * D * D;
    union { ushort_t u[8]; uint4 v; } hi, lo;
    #pragma unroll
    for (int j = 0; j < 8; ++j) split2(src[(size_t)(k0 + j) * D + n], hi.u[j], lo.u[j]);
    // swizzled Wt for gsmall
    int c8s = c8 ^ (n & 15);
    ushort_t* dhi = Wt + (size_t)l * WT2_L + n * KP2 + c8s * 8;
    *(uint4*)dhi = hi.v;
    *(uint4*)(dhi + HL2) = lo.v;
    // fragment-major Wm for mlp3
    int ct = n >> 4, m16 = n & 15, kc = c8 >> 2, qq = c8 & 3;
    int lane = qq * 16 + m16;
    ushort_t* d2 = Wm + (size_t)l * WT2_L + ((ct * 4 + kc) * 2 + 0) * 512 + lane * 8;
    *(uint4*)d2 = hi.v;
    *(uint4*)(d2 + 512) = lo.v;     // hl=1
}

// ---------------- fused 3-layer MLP for rows [5000,160000) ---------------------
// B-fragments in REGISTERS: per kc-half phase, 16 coalesced 1KB wave-loads from
// the L2-resident fragment-major Wm, then 48 pure-register MFMAs. No W in LDS,
// no staging barriers. LDS = 33.8KB scr only -> multiple independent blocks/CU.
// Block = 256 thr = 4 waves = 2 pairs x 32 rows (64 rows/block).
__global__ __launch_bounds__(256, 2)
void mlp3_kernel(const float* __restrict__ x, const ushort_t* __restrict__ Wm,
                 const float* __restrict__ bs, float* __restrict__ out) {
    __shared__ float scr[2][2][16][132];   // 33792 B
    int tid = threadIdx.x;
    int w = tid >> 6, lane = tid & 63, q = lane >> 4, m16 = lane & 15;
    int p = w >> 1, h = w & 1;             // pair index, column-half index
    int row0 = NODES_REAL + blockIdx.x * 64 + p * 32;

    // layer-0 A prefetch into registers (HBM latency hidden under layer-0 B loads)
    float4 xa[2][4][2];
    #pragma unroll
    for (int rt = 0; rt < 2; ++rt) {
        int r = row0 + rt * 16 + m16;
        if (r > NODES_TOTAL - 1) r = NODES_TOTAL - 1;
        #pragma unroll
        for (int kc = 0; kc < 4; ++kc) {
            const float* gp = x + (size_t)r * D + kc * 32 + q * 8;
            xa[rt][kc][0] = *(const float4*)gp;
            xa[rt][kc][1] = *(const float4*)(gp + 4);
        }
    }

    f32x4 acc[2][4];
    #pragma unroll
    for (int l = 0; l < 3; ++l) {
        const ushort_t* Wml = Wm + (size_t)l * WT2_L;
        if (l > 0) __syncthreads();        // (1) prev layer's scr writes visible

        // A for this layer -> bf16 hi/lo registers (all 4 kc upfront)
        BF8 ahi[2][4], alo[2][4];
        #pragma unroll
        for (int rt = 0; rt < 2; ++rt)
            #pragma unroll
            for (int kc = 0; kc < 4; ++kc) {
                float4 v0, v1;
                if (l == 0) { v0 = xa[rt][kc][0]; v1 = xa[rt][kc][1]; }
                else {
                    const float* sp = &scr[p][rt][m16][kc * 32 + q * 8];
                    v0 = *(const float4*)sp; v1 = *(const float4*)(sp + 4);
                }
                float xv[8] = {v0.x, v0.y, v0.z, v0.w, v1.x, v1.y, v1.z, v1.w};
                #pragma unroll
                for (int j = 0; j < 8; ++j) split2(xv[j], ahi[rt][kc].u[j], alo[rt][kc].u[j]);
            }
        if (l > 0) __syncthreads();        // (2) all scr reads done; writes below safe

        #pragma unroll
        for (int rt = 0; rt < 2; ++rt)
            #pragma unroll
            for (int ct = 0; ct < 4; ++ct) acc[rt][ct] = (f32x4){0.f, 0.f, 0.f, 0.f};

        // two kc-half phases: 16 coalesced B loads, then 48 register MFMAs
        #pragma unroll
        for (int ph = 0; ph < 2; ++ph) {
            int kc0 = ph * 2;
            bf16x8 bh[4][2], bl[4][2];
            #pragma unroll
            for (int ct = 0; ct < 4; ++ct)
                #pragma unroll
                for (int dk = 0; dk < 2; ++dk) {
                    const ushort_t* bp = Wml + (((h * 4 + ct) * 4 + (kc0 + dk)) * 2) * 512 + lane * 8;
                    bh[ct][dk] = *(const bf16x8*)bp;
                    bl[ct][dk] = *(const bf16x8*)(bp + 512);
                }
            #pragma unroll
            for (int dk = 0; dk < 2; ++dk)
                #pragma unroll
                for (int ct = 0; ct < 4; ++ct)
                    #pragma unroll
                    for (int rt = 0; rt < 2; ++rt) {
                        acc[rt][ct] = __builtin_amdgcn_mfma_f32_16x16x32_bf16(ahi[rt][kc0 + dk].v, bh[ct][dk], acc[rt][ct], 0, 0, 0);
                        acc[rt][ct] = __builtin_amdgcn_mfma_f32_16x16x32_bf16(ahi[rt][kc0 + dk].v, bl[ct][dk], acc[rt][ct], 0, 0, 0);
                        acc[rt][ct] = __builtin_amdgcn_mfma_f32_16x16x32_bf16(alo[rt][kc0 + dk].v, bh[ct][dk], acc[rt][ct], 0, 0, 0);
                    }
        }
        // relu(h2 + b) -> pair-shared scratch (disjoint col halves per wave)
        float bv[4];
        #pragma unroll
        for (int ct = 0; ct < 4; ++ct) bv[ct] = bs[l * D + (h * 4 + ct) * 16 + m16];
        #pragma unroll
        for (int rt = 0; rt < 2; ++rt)
            #pragma unroll
            for (int ct = 0; ct < 4; ++ct)
                #pragma unroll
                for (int reg = 0; reg < 4; ++reg)
                    scr[p][rt][q * 4 + reg][(h * 4 + ct) * 16 + m16] =
                        fmaxf(acc[rt][ct][reg] + bv[ct], 0.f);
    }
    __syncthreads();   // partner's final scr writes visible for epilogue
    // coalesced epilogue: each wave streams its 16 rows (rt = h) x 128 cols
    #pragma unroll
    for (int i = 0; i < 8; ++i) {
        int rowl = i * 2 + (lane >> 5);          // 0..15
        int grow = row0 + h * 16 + rowl;
        float4 v = *(const float4*)&scr[p][h][rowl][(lane & 31) * 4];
        if (grow < NODES_TOTAL)
            *(float4*)&out[(size_t)grow * D + (lane & 31) * 4] = v;
    }
}

// ---------------- small GEMM (rows<5000) + fused scores + per-layer max --------
__global__ __launch_bounds__(256)
void gsmall_kernel(const float* __restrict__ hin, const ushort_t* __restrict__ Wlg,
                   const float* __restrict__ a_s, const float* __restrict__ a_d,
                   float* __restrict__ h2, float* __restrict__ sv, float* __restrict__ dv,
                   uint_t* __restrict__ gmaxu) {
    __shared__ ushort_t Wl[WT2_L];         // 64 KB
    int tid = threadIdx.x;
    {
        const uint4* gw = (const uint4*)Wlg;
        uint4* lw = (uint4*)Wl;
        #pragma unroll
        for (int r = 0; r < 16; ++r) lw[r * 256 + tid] = gw[r * 256 + tid];
    }
    int w = tid >> 6, lane = tid & 63, q = lane >> 4, m16 = lane & 15;
    int row0 = blockIdx.x * 128 + w * 32;
    f32x4 acc[2][8];
    #pragma unroll
    for (int rt = 0; rt < 2; ++rt)
        #pragma unroll
        for (int ct = 0; ct < 8; ++ct) acc[rt][ct] = (f32x4){0.f, 0.f, 0.f, 0.f};
    // prefetch A while W stages
    float4 xa[2][4][2];
    #pragma unroll
    for (int rt = 0; rt < 2; ++rt) {
        int r = row0 + rt * 16 + m16;
        if (r > NODES_REAL - 1) r = NODES_REAL - 1;
        #pragma unroll
        for (int kc = 0; kc < 4; ++kc) {
            const float* gp = hin + (size_t)r * D + kc * 32 + q * 8;
            xa[rt][kc][0] = *(const float4*)gp;
            xa[rt][kc][1] = *(const float4*)(gp + 4);
        }
    }
    __syncthreads();
    #pragma unroll
    for (int kc = 0; kc < 4; ++kc) {
        BF8 ahi[2], alo[2];
        #pragma unroll
        for (int rt = 0; rt < 2; ++rt) {
            float4 v0 = xa[rt][kc][0], v1 = xa[rt][kc][1];
            float xv[8] = {v0.x, v0.y, v0.z, v0.w, v1.x, v1.y, v1.z, v1.w};
            #pragma unroll
            for (int j = 0; j < 8; ++j) split2(xv[j], ahi[rt].u[j], alo[rt].u[j]);
        }
        #pragma unroll
        for (int ct = 0; ct < 8; ++ct) {
            const ushort_t* bp = Wl + (ct * 16 + m16) * KP2 + (((kc * 4 + q) ^ m16) * 8);
            bf16x8 bhi = *(const bf16x8*)bp;
            bf16x8 blo = *(const bf16x8*)(bp + HL2);
            #pragma unroll
            for (int rt = 0; rt < 2; ++rt) {
                acc[rt][ct] = __builtin_amdgcn_mfma_f32_16x16x32_bf16(ahi[rt].v, bhi, acc[rt][ct], 0, 0, 0);
                acc[rt][ct] = __builtin_amdgcn_mfma_f32_16x16x32_bf16(ahi[rt].v, blo, acc[rt][ct], 0, 0, 0);
                acc[rt][ct] = __builtin_amdgcn_mfma_f32_16x16x32_bf16(alo[rt].v, bhi, acc[rt][ct], 0, 0, 0);
            }
        }
    }
    #pragma unroll
    for (int rt = 0; rt < 2; ++rt)
        #pragma unroll
        for (int reg = 0; reg < 4; ++reg) {
            int grow = row0 + rt * 16 + q * 4 + reg;
            if (grow < NODES_REAL) {
                #pragma unroll
                for (int ct = 0; ct < 8; ++ct)
                    h2[(size_t)grow * D + ct * 16 + m16] = acc[rt][ct][reg];
            }
        }
    float asv[8], adv[8];
    #pragma unroll
    for (int ct = 0; ct < 8; ++ct) { asv[ct] = a_s[ct * 16 + m16]; adv[ct] = a_d[ct * 16 + m16]; }
    #pragma unroll
    for (int rt = 0; rt < 2; ++rt)
        #pragma unroll
        for (int reg = 0; reg < 4; ++reg) {
            float ps = 0.f, pd = 0.f;
            #pragma unroll
            for (int ct = 0; ct < 8; ++ct) {
                float v = acc[rt][ct][reg];
                ps += v * asv[ct]; pd += v * adv[ct];
            }
            #pragma unroll
            for (int o = 1; o < 16; o <<= 1) { ps += __shfl_xor(ps, o); pd += __shfl_xor(pd, o); }
            int grow = row0 + rt * 16 + q * 4 + reg;
            if (m16 == 0 && grow < NODES_REAL) {
                sv[grow] = ps; dv[grow] = pd;
                atomicMax(gmaxu, encmax(ps));
            }
        }
}

// ---------------- aggregation: one wave per dst, global-bound softmax ----------
__global__ __launch_bounds__(256)
void agg_kernel(const float* __restrict__ h2, const float* __restrict__ sv,
                const float* __restrict__ dv, const int* __restrict__ offs,
                const ushort_t* __restrict__ esrc, const float* __restrict__ bias,
                float* __restrict__ out, const uint_t* __restrict__ gmaxu) {
    int w = threadIdx.x >> 6, lane = threadIdx.x & 63;
    int i = blockIdx.x * 4 + w;
    int start = offs[i], end = offs[i + 1];
    float d_i = dv[i];
    float gm = decmax(*gmaxu) + d_i;       // upper bound on every incoming score
    float m = gm > 0.f ? gm : NEG * gm;    // leaky_relu monotone -> exact shift
    float ax = 0.f, ay = 0.f, ax1 = 0.f, ay1 = 0.f, exs = 0.f;
    for (int base = start; base < end; base += 64) {
        int cnt = min(64, end - base);
        int srci = (lane < cnt) ? (int)esrc[base + lane] : 0;
        float sc = sv[srci] + d_i;
        sc = sc > 0.f ? sc : NEG * sc;
        float ex = (lane < cnt) ? __expf(sc - m) : 0.f;
        exs += ex;
        if (cnt == 64) {
            #pragma unroll 4
            for (int j = 0; j < 64; j += 2) {   // 2 independent fmac chains
                int   s0 = __shfl(srci, j),     s1 = __shfl(srci, j + 1);
                float e0 = __shfl(ex, j),       e1 = __shfl(ex, j + 1);
                float2 h0 = *(const float2*)&h2[(size_t)s0 * D + 2 * lane];
                float2 h1 = *(const float2*)&h2[(size_t)s1 * D + 2 * lane];
                ax  += e0 * h0.x; ay  += e0 * h0.y;
                ax1 += e1 * h1.x; ay1 += e1 * h1.y;
            }
        } else {
            for (int j = 0; j < cnt; ++j) {
                int   src = __shfl(srci, j);
                float e   = __shfl(ex, j);
                float2 hv = *(const float2*)&h2[(size_t)src * D + 2 * lane];
                ax += e * hv.x; ay += e * hv.y;
            }
        }
    }
    ax += ax1; ay += ay1;
    float scf = sv[i] + d_i; scf = scf > 0.f ? scf : NEG * scf;
    float exf = __expf(scf - m);
    float2 hv = *(const float2*)&h2[(size_t)i * D + 2 * lane];
    ax += exf * hv.x; ay += exf * hv.y;
    #pragma unroll
    for (int o = 1; o < 64; o <<= 1) exs += __shfl_xor(exs, o);
    float rd = 1.f / (exs + exf);
    float2 b2 = *(const float2*)&bias[2 * lane];
    float2 o2 = make_float2(fmaxf(ax * rd + b2.x, 0.f), fmaxf(ay * rd + b2.y, 0.f));
    *(float2*)&out[(size_t)i * D + 2 * lane] = o2;
}

// ---------------- launcher -----------------------------------------------------
extern "C" void kernel_launch(void* const* d_in, const int* in_sizes, int n_in,
                              void* d_out, int out_size, void* d_ws, size_t ws_size,
                              hipStream_t stream) {
    const float* x   = (const float*)d_in[0];
    const int*   ei  = (const int*)d_in[1];
    const float* Ws  = (const float*)d_in[2];
    const float* as_ = (const float*)d_in[3];
    const float* ad_ = (const float*)d_in[4];
    const float* bs  = (const float*)d_in[5];
    float* out = (float*)d_out;
    int Eh = in_sizes[1] / 2;                    // 1,280,000

    char* ws = (char*)d_ws;
    float*    h2     = (float*)ws;                        //  2,560,000
    float*    bufS   = (float*)(ws + 2560000);            //  2,560,000
    float*    sv     = (float*)(ws + 5120000);            //     20,000
    float*    dv     = (float*)(ws + 5140000);            //     20,000
    int*      counts = (int*)  (ws + 5160000);            //     20,000
    int*      offs   = (int*)  (ws + 5180000);            //     20,016
    ushort_t* rank16 = (ushort_t*)(ws + 5200016);         //  2,560,000
    ushort_t* esrc   = (ushort_t*)(ws + 7760016);         //  2,560,000
    ushort_t* Wt     = (ushort_t*)(ws + 10320016);        //    196,608 (swizzled)
    uint_t*   gmaxu  = (uint_t*)(ws + 10528912);          //         12
    ushort_t* Wm     = (ushort_t*)(ws + 10528928);        //    196,608 (frag-major)

    zero_kernel<<<(NODES_REAL + 255) / 256, 256, 0, stream>>>(counts, gmaxu);
    rank_kernel<<<(Eh + 255) / 256, 256, 0, stream>>>(ei, counts, rank16, Eh);
    scan_kernel<<<1, 1024, 0, stream>>>(counts, offs);
    scatter_det<<<(Eh + 255) / 256, 256, 0, stream>>>(ei, offs, rank16, esrc, Eh);
    wsplit_kernel<<<24, 256, 0, stream>>>(Ws, Wt, Wm);

    // rows >= 5000: fused 3-layer MLP, one HBM pass (64 rows / 4-wave block)
    mlp3_kernel<<<(NODES_TOTAL - NODES_REAL + 63) / 64, 256, 0, stream>>>(x, Wm, bs, out);

    // rows < 5000: per-layer GAT pipeline
    for (int l = 0; l < 3; ++l) {
        const float* hin = (l == 0) ? x : bufS;
        float* hout = (l == 2) ? out : bufS;
        gsmall_kernel<<<(NODES_REAL + 127) / 128, 256, 0, stream>>>(
            hin, Wt + (size_t)l * WT2_L, as_ + l * D, ad_ + l * D, h2, sv, dv, gmaxu + l);
        agg_kernel<<<(NODES_REAL + 3) / 4, 256, 0, stream>>>(
            h2, sv, dv, offs, esrc, bs + l * D, hout, gmaxu + l);
    }
}